// Round 5
// baseline (24910.509 us; speedup 1.0000x reference)
//
#include <hip/hip_runtime.h>
#include <math.h>

typedef __attribute__((ext_vector_type(8))) __bf16          bf16x8;
typedef __attribute__((ext_vector_type(8))) unsigned short  ushort8;
typedef __attribute__((ext_vector_type(4))) float           f32x4;

constexpr int Bb = 128, Hh = 1024, Tt = 384, BH = Bb * Hh;
constexpr int NWG = 256, BLK = 256;

// h/x tile image: [plane2][kc16][row128][col64] ushort, swizzled:
//   byte = kc*16384 + row*128 + ((col*2) ^ ((row&7)<<4)); plane stride 262144 B
constexpr size_t SLOT_B  = 524288;                       // one (B=128,K=1024) split tile
constexpr size_t OFF_H   = 1024;
constexpr size_t OFF_W   = OFF_H + 8 * SLOT_B;           // h slots: 4 layers x 2 parity
constexpr size_t WBLK_B  = 12288;                        // per (m,jwg,kc): hi[48][64], lo[48][64]
constexpr size_t OFF_X   = OFF_W + 4096ull * WBLK_B;     // wbuf: 4 mats x 64 jwg x 16 kc
constexpr size_t WS_FULL = OFF_X + 384ull * SLOT_B;      // + xsplit (384 tiles)

__device__ __forceinline__ float b2f(unsigned short h) {
    unsigned u = ((unsigned)h) << 16;
    return __builtin_bit_cast(float, u);
}
__device__ __forceinline__ void split_bf16(float x, unsigned short& hi, unsigned short& lo) {
    unsigned u  = __builtin_bit_cast(unsigned, x);
    unsigned uh = u & 0xFFFF0000u;
    hi = (unsigned short)(uh >> 16);
    float rem = x - __builtin_bit_cast(float, uh);     // exact
    unsigned ur = __builtin_bit_cast(unsigned, rem);
    ur += 0x7FFFu + ((ur >> 16) & 1u);                 // RNE
    lo = (unsigned short)(ur >> 16);
}
__device__ __forceinline__ void split8(const float* src, ushort8& h8, ushort8& l8) {
    const float4* p4 = (const float4*)src;
    float4 a = p4[0], b = p4[1];
    float v[8] = {a.x, a.y, a.z, a.w, b.x, b.y, b.z, b.w};
    #pragma unroll
    for (int m = 0; m < 8; ++m) { unsigned short h, l; split_bf16(v[m], h, l); h8[m] = h; l8[m] = l; }
}
// cached (tiles: want L2 residency for 8x same-XCD reuse)
__device__ __forceinline__ void async16(const void* g, void* l) {
    __builtin_amdgcn_global_load_lds(
        (const __attribute__((address_space(1))) unsigned int*)g,
        (__attribute__((address_space(3))) unsigned int*)l, 16, 0, 0);
}
// non-temporal (weights: 12 MB/XCD/step stream, don't evict tiles): CPol SLC/nt = 2
__device__ __forceinline__ void async16_nt(const void* g, void* l) {
    __builtin_amdgcn_global_load_lds(
        (const __attribute__((address_space(1))) unsigned int*)g,
        (__attribute__((address_space(3))) unsigned int*)l, 16, 0, 2);
}

// ---------------- prologue kernels ----------------

// weights -> wbuf[m4][jwg64][kc16]{hi[48][64], lo[48][64]} swizzled. m: 0=Wih0 1=Whh0 2=Wih1 3=Whh1
__global__ void wsplit_kernel(const float* __restrict__ W0i, const float* __restrict__ W0h,
                              const float* __restrict__ W1i, const float* __restrict__ W1h,
                              unsigned short* __restrict__ wbuf) {
    int t = blockIdx.x * 256 + threadIdx.x;
    if (t >= 4 * 64 * 16 * 48 * 8) return;
    int g8 = t & 7;
    int r  = (t >> 3) % 48;
    int rest = (t >> 3) / 48;           // ((m*64+jwg)*16+kc)
    const float* W = (rest >> 10) == 0 ? W0i : (rest >> 10) == 1 ? W0h : (rest >> 10) == 2 ? W1i : W1h;
    int kc = rest & 15, jq = (rest >> 4) & 63;
    int gate = r >> 4, jl = r & 15;
    const float* src = W + (size_t)(gate * 1024 + jq * 16 + jl) * 1024 + kc * 64 + g8 * 8;
    ushort8 h8, l8; split8(src, h8, l8);
    unsigned short* blk = wbuf + (size_t)rest * 6144;
    int boff = r * 128 + ((g8 * 16) ^ ((r & 7) << 4));   // bytes within plane
    *(ushort8*)((char*)blk + boff)        = h8;
    *(ushort8*)((char*)blk + 6144 + boff) = l8;
}

// rand_input (B,T,H) -> xsplit[tau][plane][kc][128][64] swizzled (row = batch b)
__global__ void xsplit_kernel(const float* __restrict__ xin, char* __restrict__ xb) {
    int t = blockIdx.x * 256 + threadIdx.x;
    if (t >= 384 * 16 * 128 * 8) return;
    int c8 = t & 7, b = (t >> 3) & 127, kc = (t >> 10) & 15, tau = t >> 14;
    const float* src = xin + ((size_t)b * 384 + tau) * 1024 + kc * 64 + c8 * 8;
    ushort8 h8, l8; split8(src, h8, l8);
    int boff = b * 128 + ((c8 * 16) ^ ((b & 7) << 4));
    char* dst = xb + (size_t)tau * SLOT_B + (size_t)kc * 16384 + boff;
    *(ushort8*)dst            = h8;
    *(ushort8*)(dst + 262144) = l8;
}

// h0 -> slots 1,3 ; zeros -> slots 5,7 ; zero barrier counter
__global__ void hinit_kernel(const float* __restrict__ h0, char* __restrict__ hs, unsigned* __restrict__ cnt) {
    int t = blockIdx.x * 256 + threadIdx.x;
    if (t == 0) *cnt = 0;
    if (t >= 4 * 128 * 128) return;
    int g = t & 127, b = (t >> 7) & 127, si = t >> 14;   // si 0..3 -> slot 1,3,5,7
    ushort8 h8, l8;
    if (si < 2) {
        split8(h0 + (size_t)si * BH + (size_t)b * 1024 + g * 8, h8, l8);
    } else {
        #pragma unroll
        for (int m = 0; m < 8; ++m) { h8[m] = 0; l8[m] = 0; }
    }
    int kc = g >> 3;
    int boff = b * 128 + (((g & 7) * 16) ^ ((b & 7) << 4));
    char* dst = hs + (size_t)(si * 2 + 1) * SLOT_B + (size_t)kc * 16384 + boff;
    *(ushort8*)dst            = h8;
    *(ushort8*)(dst + 262144) = l8;
}

// ---------------- main persistent kernel ----------------

// Release: h-stores are sc1 write-through atomics, drained by __syncthreads (vmcnt 0).
// Acquire: after the poll, tid0's __threadfence() invalidates this CU's L1 + XCD L2,
// so this step's cached tile reads refill from the coherent point (round-3-verified).
__device__ __forceinline__ void grid_barrier(unsigned* cnt, unsigned target) {
    __syncthreads();
    if (threadIdx.x == 0) {
        __hip_atomic_fetch_add(cnt, 1u, __ATOMIC_RELEASE, __HIP_MEMORY_SCOPE_AGENT);
        while (__hip_atomic_load(cnt, __ATOMIC_RELAXED, __HIP_MEMORY_SCOPE_AGENT) < target)
            __builtin_amdgcn_s_sleep(1);
        __threadfence();   // acquire: invalidate stale L1/L2 before reading new h tiles
    }
    __syncthreads();
}

template<bool XS>
__global__ __launch_bounds__(BLK, 1) void gru_persistent(
    const float* __restrict__ xin,
    const float* __restrict__ bih0, const float* __restrict__ bhh0,
    const float* __restrict__ bih1, const float* __restrict__ bhh1,
    unsigned* __restrict__ cnt, char* __restrict__ ws)
{
    __shared__ char AsB[3][2][16384];   // 96 KiB: 3 bufs x {hi,lo} x [128][64] bf16 (swizzled)
    __shared__ char BsB[3][2][6144];    // 36 KiB: 3 bufs x {hi,lo} x [48][64]  bf16 (swizzled)

    char*       hs = ws + OFF_H;
    const char* wb = ws + OFF_W;
    const char* xs = ws + OFF_X;

    const int bid = blockIdx.x, layer = bid >> 6, jwg = bid & 63, jbase = jwg * 16;
    const int tid = threadIdx.x, lane = tid & 63, wave = tid >> 6;

    const float* bih = (layer & 1) ? bih1 : bih0;
    const float* bhh = (layer & 1) ? bhh1 : bhh0;
    const int jcol = jbase + (lane & 15);
    const int kcj = jcol >> 6, colj = jcol & 63;
    const float b_ir = bih[jcol],          b_hr = bhh[jcol];
    const float b_iz = bih[Hh + jcol],     b_hz = bhh[Hh + jcol];
    const float b_in = bih[2 * Hh + jcol], b_hn = bhh[2 * Hh + jcol];

    auto hoff = [&](int b, int plane) -> size_t {
        return (size_t)plane * 262144 + (size_t)kcj * 16384
             + (size_t)(b * 128 + (((colj * 2) ^ ((b & 7) << 4))));
    };

    float hreg[8];   // persistent h_old for this lane's (8 b's, jcol)

    unsigned target = NWG;
    for (int s = 0; s < Tt + 3; ++s, target += NWG) {
        const int tau = s - layer;
        if (tau >= 0 && tau < Tt) {
            const char* Axb = (layer == 0) ? (xs + (size_t)tau * SLOT_B)
                                           : (hs + (size_t)(((layer - 1) * 2) + (tau & 1)) * SLOT_B);
            const char* Ahb = hs + (size_t)((layer * 2) + ((tau - 1) & 1)) * SLOT_B;
            char*       Hd  = hs + (size_t)((layer * 2) + (tau & 1)) * SLOT_B;

            if (tau == 0) {
                if (layer < 2) {
                    #pragma unroll
                    for (int rt = 0; rt < 2; ++rt)
                        #pragma unroll
                        for (int q = 0; q < 4; ++q) {
                            int b = wave * 32 + rt * 16 + (lane >> 4) * 4 + q;
                            unsigned short hi = __hip_atomic_load(
                                (const unsigned short*)(Ahb + hoff(b, 0)),
                                __ATOMIC_RELAXED, __HIP_MEMORY_SCOPE_AGENT);
                            unsigned short lo = __hip_atomic_load(
                                (const unsigned short*)(Ahb + hoff(b, 1)),
                                __ATOMIC_RELAXED, __HIP_MEMORY_SCOPE_AGENT);
                            hreg[rt * 4 + q] = b2f(hi) + b2f(lo);
                        }
                    asm volatile("s_waitcnt vmcnt(0)" ::: "memory");  // keep DMA vmcnt bookkeeping clean
                } else {
                    #pragma unroll
                    for (int i = 0; i < 8; ++i) hreg[i] = 0.f;
                }
            }

            // ---- stage one K=64 chunk via global_load_lds (44 segs = 11/wave) ----
            auto stageDMA = [&](int ch, int nb) {
                const int kc = ch & 15;
                const bool isX = ch < 16;
                const char* Ab = isX ? Axb : Ahb;
                const int m = (layer & 1) * 2 + (isX ? 0 : 1);
                const char* Wb = wb + (size_t)((m * 64 + jwg) * 16 + kc) * WBLK_B;
                #pragma unroll
                for (int i = 0; i < 11; ++i) {
                    int seg = wave + i * 4;
                    if (seg < 32) {        // A: 2 planes x 16 segs of 1 KiB (cached)
                        int p = seg >> 4, sub = seg & 15;
                        async16(Ab + (size_t)p * 262144 + (size_t)kc * 16384
                                   + sub * 1024 + lane * 16,
                                &AsB[nb][p][sub * 1024]);
                    } else {               // B: 2 planes x 6 segs of 1 KiB (nt stream)
                        int s2 = seg - 32;
                        int p = (s2 >= 6) ? 1 : 0, sub = s2 - p * 6;
                        async16_nt(Wb + (size_t)p * 6144 + sub * 1024 + lane * 16,
                                   &BsB[nb][p][sub * 1024]);
                    }
                }
            };

            // fallback staging (no xsplit image): layer-0 X = on-the-fly split + ds_write
            auto stageF = [&](int ch, int nb) {
                if (!XS && layer == 0 && ch < 16) {
                    const int kc = ch;
                    #pragma unroll
                    for (int u = 0; u < 4; ++u) {
                        int unit = tid + u * 256;           // 0..1023
                        int r = unit >> 3, g8 = unit & 7;
                        ushort8 h8, l8;
                        split8(xin + ((size_t)r * 384 + tau) * 1024 + kc * 64 + g8 * 8, h8, l8);
                        int boff = r * 128 + ((g8 * 16) ^ ((r & 7) << 4));
                        *(ushort8*)(&AsB[nb][0][0] + boff) = h8;
                        *(ushort8*)(&AsB[nb][1][0] + boff) = l8;
                    }
                    const int m = (layer & 1) * 2;
                    const char* Wb = wb + (size_t)((m * 64 + jwg) * 16 + kc) * WBLK_B;
                    #pragma unroll
                    for (int i = 0; i < 3; ++i) {
                        int s2 = wave + i * 4;
                        int p = (s2 >= 6) ? 1 : 0, sub = s2 - p * 6;
                        async16_nt(Wb + (size_t)p * 6144 + sub * 1024 + lane * 16,
                                   &BsB[nb][p][sub * 1024]);
                    }
                } else {
                    stageDMA(ch, nb);
                }
            };

            auto compute = [&](int cur, f32x4 (&acc)[2][3]) {
                #pragma unroll
                for (int ks = 0; ks < 2; ++ks) {
                    const int kb = ks * 64 + (lane >> 4) * 16;   // byte offset in k
                    bf16x8 Ah[2], Al[2], Bh[3], Bl[3];
                    #pragma unroll
                    for (int rt = 0; rt < 2; ++rt) {
                        int row = wave * 32 + rt * 16 + (lane & 15);
                        int off = row * 128 + (kb ^ ((row & 7) << 4));
                        Ah[rt] = __builtin_bit_cast(bf16x8, *(const ushort8*)(&AsB[cur][0][0] + off));
                        Al[rt] = __builtin_bit_cast(bf16x8, *(const ushort8*)(&AsB[cur][1][0] + off));
                    }
                    #pragma unroll
                    for (int g = 0; g < 3; ++g) {
                        int row = g * 16 + (lane & 15);
                        int off = row * 128 + (kb ^ ((row & 7) << 4));
                        Bh[g] = __builtin_bit_cast(bf16x8, *(const ushort8*)(&BsB[cur][0][0] + off));
                        Bl[g] = __builtin_bit_cast(bf16x8, *(const ushort8*)(&BsB[cur][1][0] + off));
                    }
                    #pragma unroll
                    for (int rt = 0; rt < 2; ++rt)
                        #pragma unroll
                        for (int g = 0; g < 3; ++g) {
                            f32x4 c = acc[rt][g];
                            c = __builtin_amdgcn_mfma_f32_16x16x32_bf16(Ah[rt], Bh[g], c, 0, 0, 0);
                            c = __builtin_amdgcn_mfma_f32_16x16x32_bf16(Al[rt], Bh[g], c, 0, 0, 0);
                            c = __builtin_amdgcn_mfma_f32_16x16x32_bf16(Ah[rt], Bl[g], c, 0, 0, 0);
                            acc[rt][g] = c;
                        }
                }
            };

            f32x4 accX[2][3], accH[2][3];
            const f32x4 zv = {0.f, 0.f, 0.f, 0.f};
            #pragma unroll
            for (int rt = 0; rt < 2; ++rt)
                #pragma unroll
                for (int g = 0; g < 3; ++g) { accX[rt][g] = zv; accH[rt][g] = zv; }

            if (XS) {
                // 3-deep pipeline, counted vmcnt (11 loads/wave/stage), raw barriers
                stageDMA(0, 0);
                stageDMA(1, 1);
                for (int ch = 0; ch < 32; ++ch) {
                    const int cur = ch % 3;
                    if (ch < 30) stageDMA(ch + 2, (ch + 2) % 3);
                    if (ch < 30)       asm volatile("s_waitcnt vmcnt(22) lgkmcnt(0)" ::: "memory");
                    else if (ch == 30) asm volatile("s_waitcnt vmcnt(11) lgkmcnt(0)" ::: "memory");
                    else               asm volatile("s_waitcnt vmcnt(0) lgkmcnt(0)"  ::: "memory");
                    __builtin_amdgcn_s_barrier();            // B1: all waves' cur-loads landed
                    asm volatile("" ::: "memory");
                    if (ch < 16) compute(cur, accX); else compute(cur, accH);
                    asm volatile("" ::: "memory");
                    __builtin_amdgcn_s_barrier();            // B2: all waves done reading cur
                    asm volatile("" ::: "memory");
                }
            } else {
                stageF(0, 0);
                __syncthreads();
                for (int ch = 0; ch < 32; ++ch) {
                    const int cur = ch & 1;
                    if (ch + 1 < 32) stageF(ch + 1, cur ^ 1);
                    if (ch < 16) compute(cur, accX); else compute(cur, accH);
                    __syncthreads();
                }
            }

            // ---- gates + state update; h written as write-through atomic bf16 pairs ----
            #pragma unroll
            for (int rt = 0; rt < 2; ++rt)
                #pragma unroll
                for (int q = 0; q < 4; ++q) {
                    const int b = wave * 32 + rt * 16 + (lane >> 4) * 4 + q;
                    float xr = accX[rt][0][q], hr = accH[rt][0][q];
                    float xz = accX[rt][1][q], hz = accH[rt][1][q];
                    float xn = accX[rt][2][q], hn_ = accH[rt][2][q];
                    float r  = 1.0f / (1.0f + expf(-(xr + b_ir + hr + b_hr)));
                    float z  = 1.0f / (1.0f + expf(-(xz + b_iz + hz + b_hz)));
                    float n  = tanhf(xn + b_in + r * (hn_ + b_hn));
                    float h  = (1.0f - z) * n + z * hreg[rt * 4 + q];
                    hreg[rt * 4 + q] = h;
                    unsigned short hi, lo; split_bf16(h, hi, lo);
                    __hip_atomic_store((unsigned short*)(Hd + hoff(b, 0)), hi,
                                       __ATOMIC_RELAXED, __HIP_MEMORY_SCOPE_AGENT);
                    __hip_atomic_store((unsigned short*)(Hd + hoff(b, 1)), lo,
                                       __ATOMIC_RELAXED, __HIP_MEMORY_SCOPE_AGENT);
                }
        }
        grid_barrier(cnt, target);
    }
}

__global__ void pred_kernel(const char* __restrict__ hs,
                            const float* __restrict__ linW,
                            const float* __restrict__ linb,
                            float* __restrict__ out) {
    const int b = blockIdx.x, l = threadIdx.x;   // 64 threads
    const char* slot = hs + 7 * SLOT_B;
    float s = 0.f;
    for (int u = l; u < Hh; u += 64) {
        int kc = u >> 6, col = u & 63;
        size_t o = (size_t)kc * 16384 + (size_t)(b * 128 + (((col * 2) ^ ((b & 7) << 4))));
        float hv = b2f(*(const unsigned short*)(slot + o))
                 + b2f(*(const unsigned short*)(slot + 262144 + o));
        s += hv * linW[u];
    }
    #pragma unroll
    for (int off = 32; off > 0; off >>= 1) s += __shfl_down(s, off);
    if (l == 0) out[b] = s + linb[0];
}

extern "C" void kernel_launch(void* const* d_in, const int* in_sizes, int n_in,
                              void* d_out, int out_size, void* d_ws, size_t ws_size,
                              hipStream_t stream) {
    const float* rand_in = (const float*)d_in[1];
    const float* h0      = (const float*)d_in[2];
    const float* Wih0    = (const float*)d_in[7];
    const float* Whh0    = (const float*)d_in[8];
    const float* bih0    = (const float*)d_in[9];
    const float* bhh0    = (const float*)d_in[10];
    const float* Wih1    = (const float*)d_in[11];
    const float* Whh1    = (const float*)d_in[12];
    const float* bih1    = (const float*)d_in[13];
    const float* bhh1    = (const float*)d_in[14];
    const float* linW    = (const float*)d_in[15];
    const float* linb    = (const float*)d_in[16];
    float* out = (float*)d_out;

    char*     ws  = (char*)d_ws;
    unsigned* cnt = (unsigned*)d_ws;
    char*     hsl = ws + OFF_H;

    const bool xsl = (ws_size >= WS_FULL);

    wsplit_kernel<<<6144, 256, 0, stream>>>(Wih0, Whh0, Wih1, Whh1,
                                            (unsigned short*)(ws + OFF_W));
    hinit_kernel<<<256, 256, 0, stream>>>(h0, hsl, cnt);
    if (xsl) {
        xsplit_kernel<<<24576, 256, 0, stream>>>(rand_in, ws + OFF_X);
        gru_persistent<true><<<NWG, BLK, 0, stream>>>(rand_in, bih0, bhh0, bih1, bhh1, cnt, ws);
    } else {
        gru_persistent<false><<<NWG, BLK, 0, stream>>>(rand_in, bih0, bhh0, bih1, bhh1, cnt, ws);
    }
    pred_kernel<<<Bb, 64, 0, stream>>>(hsl, linW, linb, out);
}

// Round 7
// 24800.923 us; speedup vs baseline: 1.0044x; 1.0044x over previous
//
#include <hip/hip_runtime.h>
#include <math.h>

typedef __attribute__((ext_vector_type(8))) __bf16          bf16x8;
typedef __attribute__((ext_vector_type(8))) unsigned short  ushort8;
typedef __attribute__((ext_vector_type(4))) float           f32x4;

constexpr int Bb = 128, Hh = 1024, Tt = 384, BH = Bb * Hh;
constexpr int NWG = 256, BLK = 256;

// h/x tile image: [plane2][kcg16][row128][col64] ushort, swizzled:
//   byte = kcg*16384 + row*128 + ((col*2) ^ ((row&7)<<4)); plane stride 262144 B
constexpr size_t SLOT_B  = 524288;                    // one (B=128,K=1024) split tile
constexpr size_t OFF_H   = 1024;
constexpr size_t OFF_P   = OFF_H + 8 * SLOT_B;        // partials: 128 pairs x 2 x 32 KB
constexpr size_t OFF_W   = OFF_P + 128ull * 65536;
constexpr size_t WBLK_B  = 24576;                     // per (m,cg,kcg): hi[96][64], lo[96][64]
constexpr size_t OFF_X   = OFF_W + 2048ull * WBLK_B;  // 4 mats x 32 cg x 16 kcg
constexpr size_t WS_FULL = OFF_X + 384ull * SLOT_B;

__device__ __forceinline__ float b2f(unsigned short h) {
    unsigned u = ((unsigned)h) << 16;
    return __builtin_bit_cast(float, u);
}
__device__ __forceinline__ void split_bf16(float x, unsigned short& hi, unsigned short& lo) {
    unsigned u  = __builtin_bit_cast(unsigned, x);
    unsigned uh = u & 0xFFFF0000u;
    hi = (unsigned short)(uh >> 16);
    float rem = x - __builtin_bit_cast(float, uh);     // exact
    unsigned ur = __builtin_bit_cast(unsigned, rem);
    ur += 0x7FFFu + ((ur >> 16) & 1u);                 // RNE
    lo = (unsigned short)(ur >> 16);
}
__device__ __forceinline__ void split8(const float* src, ushort8& h8, ushort8& l8) {
    const float4* p4 = (const float4*)src;
    float4 a = p4[0], b = p4[1];
    float v[8] = {a.x, a.y, a.z, a.w, b.x, b.y, b.z, b.w};
    #pragma unroll
    for (int m = 0; m < 8; ++m) { unsigned short h, l; split_bf16(v[m], h, l); h8[m] = h; l8[m] = l; }
}
__device__ __forceinline__ void async16(const void* g, void* l) {
    __builtin_amdgcn_global_load_lds(
        (const __attribute__((address_space(1))) unsigned int*)g,
        (__attribute__((address_space(3))) unsigned int*)l, 16, 0, 0);
}
// coherent (bypass L1+L2, read from coherent point): CPol SC0|SC1
__device__ __forceinline__ void async16_coh(const void* g, void* l) {
    __builtin_amdgcn_global_load_lds(
        (const __attribute__((address_space(1))) unsigned int*)g,
        (__attribute__((address_space(3))) unsigned int*)l, 16, 0, 17);
}
__device__ __forceinline__ void storex4_far(void* p, f32x4 v) {
    asm volatile("global_store_dwordx4 %0, %1, off sc0 sc1" :: "v"(p), "v"(v) : "memory");
}
__device__ __forceinline__ f32x4 loadx4_far(const void* p) {
    f32x4 r;
    asm volatile("global_load_dwordx4 %0, %1, off sc0 sc1" : "=v"(r) : "v"(p) : "memory");
    return r;
}

// ---------------- prologue kernels ----------------

// weights -> wbuf[(m*32+cg)*16+kcg]{hi[96][64], lo[96][64]} swizzled.
// gate-row gc in [0,96): ct=gc>>4 (=jh*3+g), jl=gc&15; weight row = g*1024 + cg*32 + jh*16 + jl
__global__ void wsplit_kernel(const float* __restrict__ W0i, const float* __restrict__ W0h,
                              const float* __restrict__ W1i, const float* __restrict__ W1h,
                              char* __restrict__ wbuf) {
    int t = blockIdx.x * 256 + threadIdx.x;
    if (t >= 2048 * 96 * 8) return;
    int g8 = t & 7;
    int gc = (t >> 3) % 96;
    int rest = (t >> 3) / 96;                // (m*32+cg)*16 + kcg
    int kcg = rest & 15, cg = (rest >> 4) & 31, m = rest >> 9;
    const float* W = (m == 0) ? W0i : (m == 1) ? W0h : (m == 2) ? W1i : W1h;
    int ct = gc >> 4, jl = gc & 15;
    int jh = ct / 3, g = ct % 3;
    const float* src = W + (size_t)(g * 1024 + cg * 32 + jh * 16 + jl) * 1024 + kcg * 64 + g8 * 8;
    ushort8 h8, l8; split8(src, h8, l8);
    char* blk = wbuf + (size_t)rest * WBLK_B;
    int boff = gc * 128 + ((g8 * 16) ^ ((gc & 7) << 4));
    *(ushort8*)(blk + boff)         = h8;
    *(ushort8*)(blk + 12288 + boff) = l8;
}

// rand_input (B,T,H) -> xsplit[tau][plane][kcg][128][64] swizzled (row = batch b)
__global__ void xsplit_kernel(const float* __restrict__ xin, char* __restrict__ xb) {
    int t = blockIdx.x * 256 + threadIdx.x;
    if (t >= 384 * 16 * 128 * 8) return;
    int c8 = t & 7, b = (t >> 3) & 127, kc = (t >> 10) & 15, tau = t >> 14;
    const float* src = xin + ((size_t)b * 384 + tau) * 1024 + kc * 64 + c8 * 8;
    ushort8 h8, l8; split8(src, h8, l8);
    int boff = b * 128 + ((c8 * 16) ^ ((b & 7) << 4));
    char* dst = xb + (size_t)tau * SLOT_B + (size_t)kc * 16384 + boff;
    *(ushort8*)dst            = h8;
    *(ushort8*)(dst + 262144) = l8;
}

// h0 -> slots 1,3 ; zeros -> slots 5,7 ; zero grid counter
__global__ void hinit_kernel(const float* __restrict__ h0, char* __restrict__ ws) {
    int t = blockIdx.x * 256 + threadIdx.x;
    if (t == 0) *(unsigned*)ws = 0;
    if (t >= 4 * 128 * 128) return;
    char* hs = ws + OFF_H;
    int g = t & 127, b = (t >> 7) & 127, si = t >> 14;   // si 0..3 -> slot 1,3,5,7
    ushort8 h8, l8;
    if (si < 2) {
        split8(h0 + (size_t)si * BH + (size_t)b * 1024 + g * 8, h8, l8);
    } else {
        #pragma unroll
        for (int m = 0; m < 8; ++m) { h8[m] = 0; l8[m] = 0; }
    }
    int kc = g >> 3;
    int boff = b * 128 + (((g & 7) * 16) ^ ((b & 7) << 4));
    char* dst = hs + (size_t)(si * 2 + 1) * SLOT_B + (size_t)kc * 16384 + boff;
    *(ushort8*)dst            = h8;
    *(ushort8*)(dst + 262144) = l8;
}

// ---------------- main persistent kernel ----------------

__device__ __forceinline__ void grid_barrier(unsigned* cnt, unsigned target) {
    __syncthreads();   // drains vmcnt(0): all prior global stores at coherent point
    if (threadIdx.x == 0) {
        __hip_atomic_fetch_add(cnt, 1u, __ATOMIC_RELEASE, __HIP_MEMORY_SCOPE_AGENT);
        while (__hip_atomic_load(cnt, __ATOMIC_RELAXED, __HIP_MEMORY_SCOPE_AGENT) < target)
            __builtin_amdgcn_s_sleep(1);
    }
    __syncthreads();
}

template<bool XS>
__global__ __launch_bounds__(BLK, 1) void gru_persistent(
    const float* __restrict__ xin,
    const float* __restrict__ bih0, const float* __restrict__ bhh0,
    const float* __restrict__ bih1, const float* __restrict__ bhh1,
    unsigned* __restrict__ cnt, char* __restrict__ ws)
{
    __shared__ char AsB[3][2][16384];   // 96 KiB: A 3-deep x {hi,lo} x [128][64] bf16
    __shared__ char BsB[2][2][12288];   // 48 KiB: B 2-deep x {hi,lo} x [96][64]  bf16

    char*       hs = ws + OFF_H;
    const char* wb = ws + OFF_W;
    const char* xs = ws + OFF_X;

    const int bid = blockIdx.x, layer = bid >> 6;
    const int w6 = bid & 63, khalf = w6 >> 5, cg = w6 & 31;
    const int jbase = cg * 32;
    const int pairid = layer * 32 + cg;
    const int tid = threadIdx.x, lane = tid & 63, wave = tid >> 6;

    const float* bih = (layer & 1) ? bih1 : bih0;
    const float* bhh = (layer & 1) ? bhh1 : bhh0;
    const int jl = lane & 15;
    const int jcol = jbase + khalf * 16 + jl;           // owned column
    const int kcj = jcol >> 6, colj = jcol & 63;
    const float b_ir = bih[jcol],          b_hr = bhh[jcol];
    const float b_iz = bih[Hh + jcol],     b_hz = bhh[Hh + jcol];
    const float b_in = bih[2 * Hh + jcol], b_hn = bhh[2 * Hh + jcol];

    char*       myP = ws + OFF_P + (size_t)pairid * 65536 + (size_t)khalf * 32768;
    const char* thP = ws + OFF_P + (size_t)pairid * 65536 + (size_t)(1 - khalf) * 32768;
    const int cto = khalf * 3, ctp = (1 - khalf) * 3;

    auto hoff = [&](int b, int plane) -> size_t {
        return (size_t)plane * 262144 + (size_t)kcj * 16384
             + (size_t)(b * 128 + (((colj * 2) ^ ((b & 7) << 4))));
    };

    float hreg[8];          // persistent h_old for this lane's (8 b's, jcol)
    const bool fb0 = (!XS) && (layer == 0);

    unsigned target = NWG;
    for (int s = 0; s < Tt + 3; ++s) {
        const int tau = s - layer;
        const bool active = (tau >= 0 && tau < Tt);
        f32x4 accX[2][6], accH[2][6];

        if (active) {
            const char* Axb = (layer == 0) ? (xs + (size_t)tau * SLOT_B)
                                           : (hs + (size_t)(((layer - 1) * 2) + (tau & 1)) * SLOT_B);
            const char* Ahb = hs + (size_t)((layer * 2) + ((tau - 1) & 1)) * SLOT_B;

            if (tau == 0) {
                if (layer < 2) {
                    #pragma unroll
                    for (int rt = 0; rt < 2; ++rt)
                        #pragma unroll
                        for (int q = 0; q < 4; ++q) {
                            int b = wave * 32 + rt * 16 + (lane >> 4) * 4 + q;
                            unsigned short hi = __hip_atomic_load(
                                (const unsigned short*)(Ahb + hoff(b, 0)),
                                __ATOMIC_RELAXED, __HIP_MEMORY_SCOPE_AGENT);
                            unsigned short lo = __hip_atomic_load(
                                (const unsigned short*)(Ahb + hoff(b, 1)),
                                __ATOMIC_RELAXED, __HIP_MEMORY_SCOPE_AGENT);
                            hreg[rt * 4 + q] = b2f(hi) + b2f(lo);
                        }
                    asm volatile("s_waitcnt vmcnt(0)" ::: "memory");
                } else {
                    #pragma unroll
                    for (int i = 0; i < 8; ++i) hreg[i] = 0.f;
                }
            }

            // ---- staging: iter ch in [0,16): ch<8 = X-stream, else H-stream; kcg = khalf*8 + (ch&7)
            auto stage_A = [&](int ch) {                 // 32 segs -> 8/wave, A 3-deep
                const int kcg = khalf * 8 + (ch & 7);
                const int nb = ch % 3;
                const bool isX = ch < 8;
                const char* Ab = isX ? Axb : Ahb;
                const bool coh = !(isX && layer == 0);   // dynamic h tiles: coherent
                #pragma unroll
                for (int i = 0; i < 8; ++i) {
                    int seg = wave + i * 4;
                    int p = seg >> 4, sub = seg & 15;
                    const char* g = Ab + (size_t)p * 262144 + (size_t)kcg * 16384
                                  + sub * 1024 + lane * 16;
                    char* l = &AsB[nb][p][sub * 1024];
                    if (coh) async16_coh(g, l); else async16(g, l);
                }
            };
            auto stage_B = [&](int ch) {                 // 24 segs -> 6/wave, B 2-deep
                const int kcg = khalf * 8 + (ch & 7);
                const int nb = ch & 1;
                const int m = (layer & 1) * 2 + (ch < 8 ? 0 : 1);
                const char* Wb = wb + (size_t)(((m * 32 + cg) << 4) + kcg) * WBLK_B;
                #pragma unroll
                for (int i = 0; i < 6; ++i) {
                    int s2 = wave + i * 4;
                    int p = (s2 >= 12) ? 1 : 0, sub = s2 - 12 * p;
                    async16(Wb + (size_t)p * 12288 + sub * 1024 + lane * 16,
                            &BsB[nb][p][sub * 1024]);
                }
            };
            auto stageFX = [&](int ch) {                 // fallback: layer-0 X on-the-fly split
                const int kcg = khalf * 8 + (ch & 7);
                const int nb = ch % 3;
                #pragma unroll
                for (int u = 0; u < 4; ++u) {
                    int unit = tid + u * 256;
                    int r = unit >> 3, g8 = unit & 7;
                    ushort8 h8, l8;
                    split8(xin + ((size_t)r * 384 + tau) * 1024 + kcg * 64 + g8 * 8, h8, l8);
                    int boff = r * 128 + ((g8 * 16) ^ ((r & 7) << 4));
                    *(ushort8*)(&AsB[nb][0][0] + boff) = h8;
                    *(ushort8*)(&AsB[nb][1][0] + boff) = l8;
                }
                asm volatile("s_waitcnt lgkmcnt(0)" ::: "memory");
            };

            auto compute = [&](int ch, f32x4 (&acc)[2][6]) {
                const int nb3 = ch % 3, nb2 = ch & 1;
                #pragma unroll
                for (int ks = 0; ks < 2; ++ks) {
                    const int kb = ks * 64 + (lane >> 4) * 16;
                    bf16x8 Ah[2], Al[2];
                    #pragma unroll
                    for (int rt = 0; rt < 2; ++rt) {
                        int row = wave * 32 + rt * 16 + (lane & 15);
                        int off = row * 128 + (kb ^ ((row & 7) << 4));
                        Ah[rt] = __builtin_bit_cast(bf16x8, *(const ushort8*)(&AsB[nb3][0][0] + off));
                        Al[rt] = __builtin_bit_cast(bf16x8, *(const ushort8*)(&AsB[nb3][1][0] + off));
                    }
                    bf16x8 Bh[6], Bl[6];
                    #pragma unroll
                    for (int ct = 0; ct < 6; ++ct) {
                        int row = ct * 16 + (lane & 15);
                        int off = row * 128 + (kb ^ ((row & 7) << 4));
                        Bh[ct] = __builtin_bit_cast(bf16x8, *(const ushort8*)(&BsB[nb2][0][0] + off));
                        Bl[ct] = __builtin_bit_cast(bf16x8, *(const ushort8*)(&BsB[nb2][1][0] + off));
                    }
                    #pragma unroll
                    for (int rt = 0; rt < 2; ++rt)
                        #pragma unroll
                        for (int ct = 0; ct < 6; ++ct) {
                            f32x4 c = acc[rt][ct];
                            c = __builtin_amdgcn_mfma_f32_16x16x32_bf16(Ah[rt], Bh[ct], c, 0, 0, 0);
                            c = __builtin_amdgcn_mfma_f32_16x16x32_bf16(Al[rt], Bh[ct], c, 0, 0, 0);
                            c = __builtin_amdgcn_mfma_f32_16x16x32_bf16(Ah[rt], Bl[ct], c, 0, 0, 0);
                            acc[rt][ct] = c;
                        }
                }
            };

            const f32x4 zv = {0.f, 0.f, 0.f, 0.f};
            #pragma unroll
            for (int rt = 0; rt < 2; ++rt)
                #pragma unroll
                for (int ct = 0; ct < 6; ++ct) { accX[rt][ct] = zv; accH[rt][ct] = zv; }

            // prologue: A(0), B(0), A(1)  (issue order matters for vmcnt counting)
            if (fb0) stageFX(0); else stage_A(0);
            stage_B(0);
            if (fb0) stageFX(1); else stage_A(1);

            // 16 iters, ONE barrier each: [wait; bar; stage_B(ch+1); stage_A(ch+2); compute(ch)]
            for (int ch = 0; ch < 16; ++ch) {
                if (fb0 || ch == 15) asm volatile("s_waitcnt vmcnt(0)" ::: "memory");
                else                 asm volatile("s_waitcnt vmcnt(8)" ::: "memory");
                __builtin_amdgcn_s_barrier();
                asm volatile("" ::: "memory");
                if (ch + 1 < 16) stage_B(ch + 1);
                if (ch + 2 < 16) {
                    if (fb0 && (ch + 2) < 8) stageFX(ch + 2);
                    else                     stage_A(ch + 2);
                }
                if (ch < 8) compute(ch, accX); else compute(ch, accH);
                asm volatile("" ::: "memory");
            }

            // ---- store partials for partner's 16 jcols (far-coherent) ----
            #pragma unroll
            for (int rt = 0; rt < 2; ++rt)
                #pragma unroll
                for (int q = 0; q < 4; ++q) {
                    int b = wave * 32 + rt * 16 + (lane >> 4) * 4 + q;
                    f32x4 pv;
                    pv[0] = accX[rt][ctp + 0][q] + accH[rt][ctp + 0][q];
                    pv[1] = accX[rt][ctp + 1][q] + accH[rt][ctp + 1][q];
                    pv[2] = accX[rt][ctp + 2][q];
                    pv[3] = accH[rt][ctp + 2][q];
                    storex4_far(myP + (size_t)(b * 16 + jl) * 16, pv);
                }
            asm volatile("s_waitcnt vmcnt(0)" ::: "memory");
        }

        // ---- global barrier #1: partials visible grid-wide (proven sync) ----
        grid_barrier(cnt, target); target += NWG;

        if (active) {
            char* Hd = hs + (size_t)((layer * 2) + (tau & 1)) * SLOT_B;

            f32x4 pp[2][4];
            #pragma unroll
            for (int rt = 0; rt < 2; ++rt)
                #pragma unroll
                for (int q = 0; q < 4; ++q) {
                    int b = wave * 32 + rt * 16 + (lane >> 4) * 4 + q;
                    pp[rt][q] = loadx4_far(thP + (size_t)(b * 16 + jl) * 16);
                }
            asm volatile("s_waitcnt vmcnt(0)" ::: "memory");
            __builtin_amdgcn_sched_barrier(0);

            // ---- gates + state update for owned 16 jcols; h as sc1 atomic bf16 pairs ----
            #pragma unroll
            for (int rt = 0; rt < 2; ++rt)
                #pragma unroll
                for (int q = 0; q < 4; ++q) {
                    const int b = wave * 32 + rt * 16 + (lane >> 4) * 4 + q;
                    f32x4 pv = pp[rt][q];
                    float rp = accX[rt][cto + 0][q] + accH[rt][cto + 0][q] + pv[0] + b_ir + b_hr;
                    float zp = accX[rt][cto + 1][q] + accH[rt][cto + 1][q] + pv[1] + b_iz + b_hz;
                    float xn = accX[rt][cto + 2][q] + pv[2] + b_in;
                    float hn = accH[rt][cto + 2][q] + pv[3] + b_hn;
                    float r  = 1.0f / (1.0f + expf(-rp));
                    float z  = 1.0f / (1.0f + expf(-zp));
                    float n  = tanhf(xn + r * hn);
                    float h  = (1.0f - z) * n + z * hreg[rt * 4 + q];
                    hreg[rt * 4 + q] = h;
                    unsigned short hi, lo; split_bf16(h, hi, lo);
                    __hip_atomic_store((unsigned short*)(Hd + hoff(b, 0)), hi,
                                       __ATOMIC_RELAXED, __HIP_MEMORY_SCOPE_AGENT);
                    __hip_atomic_store((unsigned short*)(Hd + hoff(b, 1)), lo,
                                       __ATOMIC_RELAXED, __HIP_MEMORY_SCOPE_AGENT);
                }
        }

        // ---- global barrier #2: h-state visible for next step ----
        grid_barrier(cnt, target); target += NWG;
    }
}

__global__ void pred_kernel(const char* __restrict__ hs,
                            const float* __restrict__ linW,
                            const float* __restrict__ linb,
                            float* __restrict__ out) {
    const int b = blockIdx.x, l = threadIdx.x;   // 64 threads
    const char* slot = hs + 7 * SLOT_B;
    float s = 0.f;
    for (int u = l; u < Hh; u += 64) {
        int kc = u >> 6, col = u & 63;
        size_t o = (size_t)kc * 16384 + (size_t)(b * 128 + (((col * 2) ^ ((b & 7) << 4))));
        float hv = b2f(*(const unsigned short*)(slot + o))
                 + b2f(*(const unsigned short*)(slot + 262144 + o));
        s += hv * linW[u];
    }
    #pragma unroll
    for (int off = 32; off > 0; off >>= 1) s += __shfl_down(s, off);
    if (l == 0) out[b] = s + linb[0];
}

extern "C" void kernel_launch(void* const* d_in, const int* in_sizes, int n_in,
                              void* d_out, int out_size, void* d_ws, size_t ws_size,
                              hipStream_t stream) {
    const float* rand_in = (const float*)d_in[1];
    const float* h0      = (const float*)d_in[2];
    const float* Wih0    = (const float*)d_in[7];
    const float* Whh0    = (const float*)d_in[8];
    const float* bih0    = (const float*)d_in[9];
    const float* bhh0    = (const float*)d_in[10];
    const float* Wih1    = (const float*)d_in[11];
    const float* Whh1    = (const float*)d_in[12];
    const float* bih1    = (const float*)d_in[13];
    const float* bhh1    = (const float*)d_in[14];
    const float* linW    = (const float*)d_in[15];
    const float* linb    = (const float*)d_in[16];
    float* out = (float*)d_out;

    char*     ws  = (char*)d_ws;
    unsigned* cnt = (unsigned*)d_ws;
    char*     hsl = ws + OFF_H;

    const bool xsl = (ws_size >= WS_FULL);

    wsplit_kernel<<<6144, 256, 0, stream>>>(Wih0, Whh0, Wih1, Whh1, ws + OFF_W);
    hinit_kernel<<<256, 256, 0, stream>>>(h0, ws);
    if (xsl) {
        xsplit_kernel<<<24576, 256, 0, stream>>>(rand_in, ws + OFF_X);
        gru_persistent<true><<<NWG, BLK, 0, stream>>>(rand_in, bih0, bhh0, bih1, bhh1, cnt, ws);
    } else {
        gru_persistent<false><<<NWG, BLK, 0, stream>>>(rand_in, bih0, bhh0, bih1, bhh1, cnt, ws);
    }
    pred_kernel<<<Bb, 64, 0, stream>>>(hsl, linW, linb, out);
}

// Round 8
// 21441.904 us; speedup vs baseline: 1.1618x; 1.1567x over previous
//
#include <hip/hip_runtime.h>
#include <math.h>

typedef __attribute__((ext_vector_type(8))) __bf16          bf16x8;
typedef __attribute__((ext_vector_type(8))) unsigned short  ushort8;
typedef __attribute__((ext_vector_type(4))) float           f32x4;

constexpr int Bb = 128, Hh = 1024, Tt = 384, BH = Bb * Hh;
constexpr int NWG = 128, BLK = 512;   // 4 layers x 32 col-groups, 8 waves/WG

// h/x tile image: [plane2][kcg16][row128][col64] ushort, swizzled:
//   byte = kcg*16384 + row*128 + ((col*2) ^ ((row&7)<<4)); plane stride 262144 B
constexpr size_t SLOT_B  = 524288;                    // one (B=128,K=1024) split tile
constexpr size_t OFF_H   = 1024;
constexpr size_t OFF_P   = OFF_H + 8 * SLOT_B;        // (unused this round; layout kept)
constexpr size_t OFF_W   = OFF_P + 128ull * 65536;
constexpr size_t WBLK_B  = 24576;                     // per (m,cg,kcg): hi[96][64], lo[96][64]
constexpr size_t OFF_X   = OFF_W + 2048ull * WBLK_B;  // 4 mats x 32 cg x 16 kcg
constexpr size_t WS_FULL = OFF_X + 384ull * SLOT_B;

__device__ __forceinline__ float b2f(unsigned short h) {
    unsigned u = ((unsigned)h) << 16;
    return __builtin_bit_cast(float, u);
}
__device__ __forceinline__ void split_bf16(float x, unsigned short& hi, unsigned short& lo) {
    unsigned u  = __builtin_bit_cast(unsigned, x);
    unsigned uh = u & 0xFFFF0000u;
    hi = (unsigned short)(uh >> 16);
    float rem = x - __builtin_bit_cast(float, uh);     // exact
    unsigned ur = __builtin_bit_cast(unsigned, rem);
    ur += 0x7FFFu + ((ur >> 16) & 1u);                 // RNE
    lo = (unsigned short)(ur >> 16);
}
__device__ __forceinline__ void split8(const float* src, ushort8& h8, ushort8& l8) {
    const float4* p4 = (const float4*)src;
    float4 a = p4[0], b = p4[1];
    float v[8] = {a.x, a.y, a.z, a.w, b.x, b.y, b.z, b.w};
    #pragma unroll
    for (int m = 0; m < 8; ++m) { unsigned short h, l; split_bf16(v[m], h, l); h8[m] = h; l8[m] = l; }
}
__device__ __forceinline__ void async16(const void* g, void* l) {
    __builtin_amdgcn_global_load_lds(
        (const __attribute__((address_space(1))) unsigned int*)g,
        (__attribute__((address_space(3))) unsigned int*)l, 16, 0, 0);
}
// coherent (bypass L1+L2, read from coherent point): CPol SC0|SC1
__device__ __forceinline__ void async16_coh(const void* g, void* l) {
    __builtin_amdgcn_global_load_lds(
        (const __attribute__((address_space(1))) unsigned int*)g,
        (__attribute__((address_space(3))) unsigned int*)l, 16, 0, 17);
}

// ---------------- prologue kernels (unchanged layouts) ----------------

// weights -> wbuf[(m*32+cg)*16+kcg]{hi[96][64], lo[96][64]} swizzled.
// gate-row gc in [0,96): ct=gc>>4 (=jh*3+g), jl=gc&15; weight row = g*1024 + cg*32 + jh*16 + jl
__global__ void wsplit_kernel(const float* __restrict__ W0i, const float* __restrict__ W0h,
                              const float* __restrict__ W1i, const float* __restrict__ W1h,
                              char* __restrict__ wbuf) {
    int t = blockIdx.x * 256 + threadIdx.x;
    if (t >= 2048 * 96 * 8) return;
    int g8 = t & 7;
    int gc = (t >> 3) % 96;
    int rest = (t >> 3) / 96;                // (m*32+cg)*16 + kcg
    int kcg = rest & 15, cg = (rest >> 4) & 31, m = rest >> 9;
    const float* W = (m == 0) ? W0i : (m == 1) ? W0h : (m == 2) ? W1i : W1h;
    int ct = gc >> 4, jl = gc & 15;
    int jh = ct / 3, g = ct % 3;
    const float* src = W + (size_t)(g * 1024 + cg * 32 + jh * 16 + jl) * 1024 + kcg * 64 + g8 * 8;
    ushort8 h8, l8; split8(src, h8, l8);
    char* blk = wbuf + (size_t)rest * WBLK_B;
    int boff = gc * 128 + ((g8 * 16) ^ ((gc & 7) << 4));
    *(ushort8*)(blk + boff)         = h8;
    *(ushort8*)(blk + 12288 + boff) = l8;
}

// rand_input (B,T,H) -> xsplit[tau][plane][kcg][128][64] swizzled (row = batch b)
__global__ void xsplit_kernel(const float* __restrict__ xin, char* __restrict__ xb) {
    int t = blockIdx.x * 256 + threadIdx.x;
    if (t >= 384 * 16 * 128 * 8) return;
    int c8 = t & 7, b = (t >> 3) & 127, kc = (t >> 10) & 15, tau = t >> 14;
    const float* src = xin + ((size_t)b * 384 + tau) * 1024 + kc * 64 + c8 * 8;
    ushort8 h8, l8; split8(src, h8, l8);
    int boff = b * 128 + ((c8 * 16) ^ ((b & 7) << 4));
    char* dst = xb + (size_t)tau * SLOT_B + (size_t)kc * 16384 + boff;
    *(ushort8*)dst            = h8;
    *(ushort8*)(dst + 262144) = l8;
}

// h0 -> slots 1,3 ; zeros -> slots 5,7 ; zero grid counter
__global__ void hinit_kernel(const float* __restrict__ h0, char* __restrict__ ws) {
    int t = blockIdx.x * 256 + threadIdx.x;
    if (t == 0) *(unsigned*)ws = 0;
    if (t >= 4 * 128 * 128) return;
    char* hs = ws + OFF_H;
    int g = t & 127, b = (t >> 7) & 127, si = t >> 14;   // si 0..3 -> slot 1,3,5,7
    ushort8 h8, l8;
    if (si < 2) {
        split8(h0 + (size_t)si * BH + (size_t)b * 1024 + g * 8, h8, l8);
    } else {
        #pragma unroll
        for (int m = 0; m < 8; ++m) { h8[m] = 0; l8[m] = 0; }
    }
    int kc = g >> 3;
    int boff = b * 128 + (((g & 7) * 16) ^ ((b & 7) << 4));
    char* dst = hs + (size_t)(si * 2 + 1) * SLOT_B + (size_t)kc * 16384 + boff;
    *(ushort8*)dst            = h8;
    *(ushort8*)(dst + 262144) = l8;
}

// ---------------- main persistent kernel ----------------

__device__ __forceinline__ void grid_barrier(unsigned* cnt, unsigned target) {
    __syncthreads();   // drains vmcnt(0): sc1 h-stores at coherent point
    if (threadIdx.x == 0) {
        __hip_atomic_fetch_add(cnt, 1u, __ATOMIC_RELEASE, __HIP_MEMORY_SCOPE_AGENT);
        while (__hip_atomic_load(cnt, __ATOMIC_RELAXED, __HIP_MEMORY_SCOPE_AGENT) < target)
            __builtin_amdgcn_s_sleep(1);
    }
    __syncthreads();
}

template<bool XS>
__global__ __launch_bounds__(BLK, 2) void gru_persistent(
    const float* __restrict__ xin,
    const float* __restrict__ bih0, const float* __restrict__ bhh0,
    const float* __restrict__ bih1, const float* __restrict__ bhh1,
    unsigned* __restrict__ cnt, char* __restrict__ ws)
{
    __shared__ char AsB[3][2][16384];   // 96 KiB: A 3-deep x {hi,lo} x [128][64] bf16
    __shared__ char BsB[2][2][12288];   // 48 KiB: B 2-deep x {hi,lo} x [96][64]  bf16

    char*       hs = ws + OFF_H;
    const char* wb = ws + OFF_W;
    const char* xs = ws + OFF_X;

    const int bid = blockIdx.x, layer = bid >> 5, cg = bid & 31;
    const int jbase = cg * 32;
    const int tid = threadIdx.x, lane = tid & 63, wave = tid >> 6;   // 8 waves

    const float* bih = (layer & 1) ? bih1 : bih0;
    const float* bhh = (layer & 1) ? bhh1 : bhh0;
    const int jl = lane & 15;

    // per-thread: two owned jcols (jh = 0,1)
    int   jc[2], kcj[2], colj[2];
    float b_ir[2], b_hr[2], b_iz[2], b_hz[2], b_in[2], b_hn[2];
    #pragma unroll
    for (int jh = 0; jh < 2; ++jh) {
        int j = jbase + jh * 16 + jl;
        jc[jh] = j; kcj[jh] = j >> 6; colj[jh] = j & 63;
        b_ir[jh] = bih[j];           b_hr[jh] = bhh[j];
        b_iz[jh] = bih[Hh + j];      b_hz[jh] = bhh[Hh + j];
        b_in[jh] = bih[2 * Hh + j];  b_hn[jh] = bhh[2 * Hh + j];
    }

    auto hoff = [&](int b, int plane, int jh) -> size_t {
        return (size_t)plane * 262144 + (size_t)kcj[jh] * 16384
             + (size_t)(b * 128 + (((colj[jh] * 2) ^ ((b & 7) << 4))));
    };

    float hreg[8];          // h_old for (jh 0..1) x (q 0..3); rows b = wave*16+(lane>>4)*4+q
    const bool fb0 = (!XS) && (layer == 0);

    unsigned target = NWG;
    for (int s = 0; s < Tt + 3; ++s, target += NWG) {
        const int tau = s - layer;
        if (tau >= 0 && tau < Tt) {
            const char* Axb = (layer == 0) ? (xs + (size_t)tau * SLOT_B)
                                           : (hs + (size_t)(((layer - 1) * 2) + (tau & 1)) * SLOT_B);
            const char* Ahb = hs + (size_t)((layer * 2) + ((tau - 1) & 1)) * SLOT_B;
            char*       Hd  = hs + (size_t)((layer * 2) + (tau & 1)) * SLOT_B;

            if (tau == 0) {
                if (layer < 2) {
                    #pragma unroll
                    for (int jh = 0; jh < 2; ++jh)
                        #pragma unroll
                        for (int q = 0; q < 4; ++q) {
                            int b = wave * 16 + (lane >> 4) * 4 + q;
                            unsigned short hi = __hip_atomic_load(
                                (const unsigned short*)(Ahb + hoff(b, 0, jh)),
                                __ATOMIC_RELAXED, __HIP_MEMORY_SCOPE_AGENT);
                            unsigned short lo = __hip_atomic_load(
                                (const unsigned short*)(Ahb + hoff(b, 1, jh)),
                                __ATOMIC_RELAXED, __HIP_MEMORY_SCOPE_AGENT);
                            hreg[jh * 4 + q] = b2f(hi) + b2f(lo);
                        }
                    asm volatile("s_waitcnt vmcnt(0)" ::: "memory");  // clean vmcnt ledger
                } else {
                    #pragma unroll
                    for (int i = 0; i < 8; ++i) hreg[i] = 0.f;
                }
            }

            // ---- staging: ch in [0,32): ch<16 = X (kcg=ch), else H (kcg=ch-16) ----
            auto stage_A = [&](int ch) {                 // 32 segs -> 4/wave, A 3-deep
                const int kcg = ch & 15;
                const int nb = ch % 3;
                const bool isX = ch < 16;
                const char* Ab = isX ? Axb : Ahb;
                const bool coh = !(isX && layer == 0);   // dynamic h tiles: coherent
                #pragma unroll
                for (int i = 0; i < 4; ++i) {
                    int seg = wave + i * 8;
                    int p = seg >> 4, sub = seg & 15;
                    const char* g = Ab + (size_t)p * 262144 + (size_t)kcg * 16384
                                  + sub * 1024 + lane * 16;
                    char* l = &AsB[nb][p][sub * 1024];
                    if (coh) async16_coh(g, l); else async16(g, l);
                }
            };
            auto stage_B = [&](int ch) {                 // 24 segs -> 3/wave, B 2-deep
                const int kcg = ch & 15;
                const int nb = ch & 1;
                const int m = (layer & 1) * 2 + (ch < 16 ? 0 : 1);
                const char* Wb = wb + (size_t)(((m * 32 + cg) << 4) + kcg) * WBLK_B;
                #pragma unroll
                for (int i = 0; i < 3; ++i) {
                    int s2 = wave + i * 8;
                    int p = (s2 >= 12) ? 1 : 0, sub = s2 - 12 * p;
                    async16(Wb + (size_t)p * 12288 + sub * 1024 + lane * 16,
                            &BsB[nb][p][sub * 1024]);
                }
            };
            auto stageFX = [&](int ch) {                 // fallback: layer-0 X on-the-fly split
                const int kcg = ch & 15;
                const int nb = ch % 3;
                #pragma unroll
                for (int u = 0; u < 2; ++u) {
                    int unit = tid + u * 512;            // 0..1023
                    int r = unit >> 3, g8 = unit & 7;
                    ushort8 h8, l8;
                    split8(xin + ((size_t)r * 384 + tau) * 1024 + kcg * 64 + g8 * 8, h8, l8);
                    int boff = r * 128 + ((g8 * 16) ^ ((r & 7) << 4));
                    *(ushort8*)(&AsB[nb][0][0] + boff) = h8;
                    *(ushort8*)(&AsB[nb][1][0] + boff) = l8;
                }
                asm volatile("s_waitcnt lgkmcnt(0)" ::: "memory");
            };

            auto compute = [&](int ch, f32x4 (&acc)[6]) {
                const int nb3 = ch % 3, nb2 = ch & 1;
                __builtin_amdgcn_s_setprio(1);
                #pragma unroll
                for (int ks = 0; ks < 2; ++ks) {
                    const int kb = ks * 64 + (lane >> 4) * 16;
                    int arow = wave * 16 + (lane & 15);
                    int offA = arow * 128 + (kb ^ ((arow & 7) << 4));
                    bf16x8 Ah = __builtin_bit_cast(bf16x8, *(const ushort8*)(&AsB[nb3][0][0] + offA));
                    bf16x8 Al = __builtin_bit_cast(bf16x8, *(const ushort8*)(&AsB[nb3][1][0] + offA));
                    #pragma unroll
                    for (int ct = 0; ct < 6; ++ct) {
                        int brow = ct * 16 + (lane & 15);
                        int offB = brow * 128 + (kb ^ ((brow & 7) << 4));
                        bf16x8 Bh = __builtin_bit_cast(bf16x8, *(const ushort8*)(&BsB[nb2][0][0] + offB));
                        bf16x8 Bl = __builtin_bit_cast(bf16x8, *(const ushort8*)(&BsB[nb2][1][0] + offB));
                        f32x4 c = acc[ct];
                        c = __builtin_amdgcn_mfma_f32_16x16x32_bf16(Ah, Bh, c, 0, 0, 0);
                        c = __builtin_amdgcn_mfma_f32_16x16x32_bf16(Al, Bh, c, 0, 0, 0);
                        c = __builtin_amdgcn_mfma_f32_16x16x32_bf16(Ah, Bl, c, 0, 0, 0);
                        acc[ct] = c;
                    }
                }
                __builtin_amdgcn_s_setprio(0);
            };

            f32x4 accX[6], accH[6];
            const f32x4 zv = {0.f, 0.f, 0.f, 0.f};
            #pragma unroll
            for (int ct = 0; ct < 6; ++ct) { accX[ct] = zv; accH[ct] = zv; }

            // prologue: A(0), B(0), A(1)
            if (fb0) stageFX(0); else stage_A(0);
            stage_B(0);
            if (fb0) stageFX(1); else stage_A(1);

            // 32 iters, one barrier each: [wait; bar; stage_B(ch+1); stage_A(ch+2); compute(ch)]
            for (int ch = 0; ch < 32; ++ch) {
                if (fb0 || ch == 31) asm volatile("s_waitcnt vmcnt(0)" ::: "memory");
                else                 asm volatile("s_waitcnt vmcnt(4)" ::: "memory");
                __builtin_amdgcn_s_barrier();
                asm volatile("" ::: "memory");
                if (ch + 1 < 32) stage_B(ch + 1);
                if (ch + 2 < 32) {
                    if (fb0 && (ch + 2) < 16) stageFX(ch + 2);
                    else                      stage_A(ch + 2);
                }
                if (ch < 16) compute(ch, accX); else compute(ch, accH);
                asm volatile("" ::: "memory");
            }

            // ---- gates + state update; h as sc1 atomic bf16 pairs ----
            #pragma unroll
            for (int jh = 0; jh < 2; ++jh)
                #pragma unroll
                for (int q = 0; q < 4; ++q) {
                    const int b = wave * 16 + (lane >> 4) * 4 + q;
                    float rp = accX[jh * 3 + 0][q] + accH[jh * 3 + 0][q] + b_ir[jh] + b_hr[jh];
                    float zp = accX[jh * 3 + 1][q] + accH[jh * 3 + 1][q] + b_iz[jh] + b_hz[jh];
                    float xn = accX[jh * 3 + 2][q] + b_in[jh];
                    float hn = accH[jh * 3 + 2][q] + b_hn[jh];
                    float r  = 1.0f / (1.0f + expf(-rp));
                    float z  = 1.0f / (1.0f + expf(-zp));
                    float n  = tanhf(xn + r * hn);
                    float h  = (1.0f - z) * n + z * hreg[jh * 4 + q];
                    hreg[jh * 4 + q] = h;
                    unsigned short hi, lo; split_bf16(h, hi, lo);
                    __hip_atomic_store((unsigned short*)(Hd + hoff(b, 0, jh)), hi,
                                       __ATOMIC_RELAXED, __HIP_MEMORY_SCOPE_AGENT);
                    __hip_atomic_store((unsigned short*)(Hd + hoff(b, 1, jh)), lo,
                                       __ATOMIC_RELAXED, __HIP_MEMORY_SCOPE_AGENT);
                }
        }
        grid_barrier(cnt, target);
    }
}

__global__ void pred_kernel(const char* __restrict__ hs,
                            const float* __restrict__ linW,
                            const float* __restrict__ linb,
                            float* __restrict__ out) {
    const int b = blockIdx.x, l = threadIdx.x;   // 64 threads
    const char* slot = hs + 7 * SLOT_B;
    float s = 0.f;
    for (int u = l; u < Hh; u += 64) {
        int kc = u >> 6, col = u & 63;
        size_t o = (size_t)kc * 16384 + (size_t)(b * 128 + (((col * 2) ^ ((b & 7) << 4))));
        float hv = b2f(*(const unsigned short*)(slot + o))
                 + b2f(*(const unsigned short*)(slot + 262144 + o));
        s += hv * linW[u];
    }
    #pragma unroll
    for (int off = 32; off > 0; off >>= 1) s += __shfl_down(s, off);
    if (l == 0) out[b] = s + linb[0];
}

extern "C" void kernel_launch(void* const* d_in, const int* in_sizes, int n_in,
                              void* d_out, int out_size, void* d_ws, size_t ws_size,
                              hipStream_t stream) {
    const float* rand_in = (const float*)d_in[1];
    const float* h0      = (const float*)d_in[2];
    const float* Wih0    = (const float*)d_in[7];
    const float* Whh0    = (const float*)d_in[8];
    const float* bih0    = (const float*)d_in[9];
    const float* bhh0    = (const float*)d_in[10];
    const float* Wih1    = (const float*)d_in[11];
    const float* Whh1    = (const float*)d_in[12];
    const float* bih1    = (const float*)d_in[13];
    const float* bhh1    = (const float*)d_in[14];
    const float* linW    = (const float*)d_in[15];
    const float* linb    = (const float*)d_in[16];
    float* out = (float*)d_out;

    char*     ws  = (char*)d_ws;
    unsigned* cnt = (unsigned*)d_ws;
    char*     hsl = ws + OFF_H;

    const bool xsl = (ws_size >= WS_FULL);

    wsplit_kernel<<<6144, 256, 0, stream>>>(Wih0, Whh0, Wih1, Whh1, ws + OFF_W);
    hinit_kernel<<<256, 256, 0, stream>>>(h0, ws);
    if (xsl) {
        xsplit_kernel<<<24576, 256, 0, stream>>>(rand_in, ws + OFF_X);
        gru_persistent<true><<<NWG, BLK, 0, stream>>>(rand_in, bih0, bhh0, bih1, bhh1, cnt, ws);
    } else {
        gru_persistent<false><<<NWG, BLK, 0, stream>>>(rand_in, bih0, bhh0, bih1, bhh1, cnt, ws);
    }
    pred_kernel<<<Bb, 64, 0, stream>>>(hsl, linW, linb, out);
}